// Round 3
// baseline (406.767 us; speedup 1.0000x reference)
//
#include <hip/hip_runtime.h>
#include <cmath>

// ---------------------------------------------------------------------------
// g_s: 4x chained conv_transpose2d(k=5,s=2,p=2,op=1) + integer quant epilogue.
// Hermite: sum_j floor((round(w)+j)/split) == round(w) -> one conv per layer.
// Exact i8: weights round(w) in [-127,127]; activations (x-128) in i8; OOB
// halo = -128 so conv_i8 = conv_ref(x) - 128*tapsum[parity][co] (exact i32).
//
// v10 (from v9 @263us, layer3 70.5us): v9 post-mortem — regression was vmcnt
// FIFO ordering: x-prefetch loads issued BEFORE the compute phase's b global
// loads; vmcnt retires in order, so the first MFMA's b-wait force-drained the
// x-prefetch (L2/HBM latency serialized at every chunk head). Fix:
// (a) b-fragments loaded into registers (breg[13], static constexpr indexing)
//     at ITERATION TOP, before store_x and before load_x(next). Stream order
//     [b, x-next] -> store_x waits x(ck) via vmcnt(13) keeping b in flight;
//     compute waits b via vmcnt(6) keeping x-next in flight. Pipeline restored.
// (b) launch_bounds(256,2): breg adds ~52 VGPR; don't force spills.
// (c) OOB halo via 512B -128-filled pad region (pointer redirect, no masks).
// (d) epilogue: final floorf+(int) folded to trunc-convert (operand >= 0).
// NOT touched this round: LDS bank conflicts (3.29M counter) — next lever.
// ---------------------------------------------------------------------------

typedef int int4v  __attribute__((ext_vector_type(4)));
typedef int int16v __attribute__((ext_vector_type(16)));

// tap id -> (ky,kx). Taps 0-8: EE; 9-14: EO; 15-20: OE; 21-24: OO.
__device__ __forceinline__ void tap_to_k(int t, int& ky, int& kx) {
    if (t < 9)       { int dy = t/3,  dx = t%3;                   ky = 4-2*dy; kx = 4-2*dx; }
    else if (t < 15) { int u = t-9;   int dy = u/2, dx = 1+(u&1);  ky = 4-2*dy; kx = 5-2*dx; }
    else if (t < 21) { int u = t-15;  int dy = 1+u/3, dx = u%3;    ky = 5-2*dy; kx = 4-2*dx; }
    else             { int u = t-21;  int dy = 1+u/2, dx = 1+(u&1); ky = 5-2*dy; kx = 5-2*dx; }
}

// f32 NCHW -> i8 (x-128) NHWC via LDS transpose; block(0,0) zeroes tapsums
// and fills the 512B OOB pad region with 0x80 (= -128).
__global__ __launch_bounds__(256)
void convert_x_t(const float* __restrict__ x, signed char* __restrict__ xh,
                 int* __restrict__ tsz, int ts_count, int C, int HW,
                 signed char* __restrict__ xpad) {
    if (blockIdx.x == 0 && blockIdx.y == 0) {
        for (int i = threadIdx.x; i < ts_count; i += 256) tsz[i] = 0;
        if (threadIdx.x < 128) ((int*)xpad)[threadIdx.x] = (int)0x80808080;
    }
    __shared__ float t[64][65];
    const int p0 = blockIdx.x * 64;
    const int c0 = blockIdx.y * 64;
    const int pL = threadIdx.x & 63;
    const int r0 = threadIdx.x >> 6;  // 0..3
    #pragma unroll
    for (int k = 0; k < 16; ++k) {
        int ciL = r0 * 16 + k;
        t[ciL][pL] = x[(size_t)(c0 + ciL) * HW + p0 + pL];
    }
    __syncthreads();
    #pragma unroll
    for (int k = 0; k < 16; ++k) {
        int pL2 = r0 * 16 + k;
        xh[(size_t)(p0 + pL2) * C + c0 + pL] = (signed char)((int)t[pL][pL2] - 128);
    }
}

// Fused pack+tapsum for layers 1-3. One block per 25600-B slab (qs,nb):
// stage the B-fragment slab in LDS (byte writes), copy out coalesced 16B;
// tapsum[p][co] reduced in LDS then one global atomicAdd per (p,co).
__global__ __launch_bounds__(256)
void packA(const float* __restrict__ w1, const float* __restrict__ w2,
           const float* __restrict__ w3,
           signed char* __restrict__ p1, signed char* __restrict__ p2,
           signed char* __restrict__ p3,
           int* __restrict__ t1, int* __restrict__ t2, int* __restrict__ t3) {
    const int layer = blockIdx.y;
    const float* w = (layer == 0) ? w1 : (layer == 1) ? w2 : w3;
    signed char* out = (layer == 0) ? p1 : (layer == 1) ? p2 : p3;
    int* ts = (layer == 0) ? t1 : (layer == 1) ? t2 : t3;
    const int Cout = 192;
    const int s = blockIdx.x;
    if (layer > 0 && s >= 36) return;
    const int qs = s / 6, nb = s % 6;

    __shared__ __align__(16) signed char ls[25600];
    __shared__ int lsum[4][32];
    if (threadIdx.x < 128) ((int*)lsum)[threadIdx.x] = 0;
    __syncthreads();

    #pragma unroll
    for (int k = 0; k < 4; ++k) {
        const int pidx = threadIdx.x + k * 256;   // 0..1023 = 32ci x 32co
        const int cil = pidx >> 5;
        const int col = pidx & 31;
        const int ci = qs * 32 + cil;
        const int co = nb * 32 + col;
        const float* wr = w + (size_t)(ci * Cout + co) * 25;
        const int half = cil >> 4, j = cil & 15;
        const int base = (half * 32 + col) * 16 + j;
        int psum[4] = {0, 0, 0, 0};
        #pragma unroll
        for (int t = 0; t < 25; ++t) {
            int ky, kx; tap_to_k(t, ky, kx);
            float v = rintf(wr[ky * 5 + kx]);
            v = fminf(fmaxf(v, -128.0f), 127.0f);
            int iv = (int)v;
            ls[t * 1024 + base] = (signed char)iv;
            psum[((ky & 1) << 1) | (kx & 1)] += iv;
        }
        #pragma unroll
        for (int p = 0; p < 4; ++p) atomicAdd(&lsum[p][col], psum[p]);
    }
    __syncthreads();

    signed char* dst = out + (size_t)s * 25600;
    for (int i = threadIdx.x; i < 1600; i += 256)
        *(int4v*)&dst[i * 16] = *(const int4v*)&ls[i * 16];
    if (threadIdx.x < 128) {
        const int p = threadIdx.x >> 5, col = threadIdx.x & 31;
        atomicAdd(&ts[p * Cout + nb * 32 + col], lsum[p][col]);
    }
}

// final-layer pack: N-dim = (parity,co): column c = p*8+co (co<3 live).
__global__ void pack_w4_i8(const float* __restrict__ w, signed char* __restrict__ wpk) {
    int idx = blockIdx.x * blockDim.x + threadIdx.x;
    if (idx >= 6 * 9 * 64 * 16) return;
    int j    = idx & 15;
    int lane = (idx >> 4) & 63;
    int rem  = idx >> 10;
    int s9   = rem % 9;
    int qs   = rem / 9;
    int col  = lane & 31;
    int co   = col & 7;
    int p    = col >> 3;
    int py = p >> 1, px = p & 1;
    int dy = s9 / 3, dx = s9 % 3;
    int ci = qs * 32 + ((lane >> 5) << 4) + j;
    bool part = (py == 0 || dy >= 1) && (px == 0 || dx >= 1);
    float v = 0.0f;
    if (co < 3 && part) {
        int ky = py ? 5 - 2 * dy : 4 - 2 * dy;
        int kx = px ? 5 - 2 * dx : 4 - 2 * dx;
        v = rintf(w[(size_t)(ci * 3 + co) * 25 + ky * 5 + kx]);
        v = fminf(fmaxf(v, -128.0f), 127.0f);
    }
    wpk[idx] = (signed char)(int)v;
}

// tapsum for w4 only: one 64-thread block per (p,co), 12 blocks.
__global__ __launch_bounds__(64)
void tap_w4(const float* __restrict__ w, int* __restrict__ ts) {
    const int Cin = 192, Cout = 3;
    const int i = blockIdx.x;            // p*3 + co
    const int co = i % Cout, p = i / Cout;
    const int py = p >> 1, px = p & 1;
    const int nky = (5 - py + 1) >> 1;
    const int nkx = (5 - px + 1) >> 1;
    const int ntap = nky * nkx;
    int s = 0;
    for (int idx = threadIdx.x; idx < Cin * ntap; idx += 64) {
        const int ci = idx / ntap;
        const int u  = idx - ci * ntap;
        const int ky = py + 2 * (u / nkx);
        const int kx = px + 2 * (u % nkx);
        float v = rintf(w[(size_t)(ci * Cout + co) * 25 + ky * 5 + kx]);
        v = fminf(fmaxf(v, -128.0f), 127.0f);
        s += (int)v;
    }
    #pragma unroll
    for (int off = 32; off > 0; off >>= 1)
        s += __shfl_down(s, off, 64);
    if (threadIdx.x == 0) ts[i] = s;
}

// Per-role tap tables for parity-split (role0: EE(acc0)+OO(acc1);
// role1: EO(acc0)+OE(acc1)). Verified against the full shift/tap/parity map.
__device__ __forceinline__ constexpr int role_nt(int role, int s9) {
    constexpr int NT0[9] = {1,1,1,1,2,2,1,2,2};
    constexpr int NT1[9] = {0,1,1,1,2,2,1,2,2};
    return role == 0 ? NT0[s9] : NT1[s9];
}
__device__ __forceinline__ constexpr int role_tap(int role, int s9, int u) {
    constexpr int T0[9][2] = {{0,0},{1,0},{2,0},{3,0},{4,21},{5,22},{6,0},{7,23},{8,24}};
    constexpr int T1[9][2] = {{0,0},{9,0},{10,0},{15,0},{11,16},{12,17},{18,0},{13,19},{14,20}};
    return role == 0 ? T0[s9][u] : T1[s9][u];
}
__device__ __forceinline__ constexpr int role_acc(int role, int s9, int u) {
    constexpr int A0[9][2] = {{0,0},{0,0},{0,0},{0,0},{0,1},{0,1},{0,0},{0,1},{0,1}};
    constexpr int A1[9][2] = {{0,0},{0,0},{0,0},{1,0},{0,1},{0,1},{1,0},{0,1},{0,1}};
    return role == 0 ? A0[s9][u] : A1[s9][u];
}
// linear b-register index for (s9,u) within a role (prefix count of taps)
__device__ __forceinline__ constexpr int role_bidx(int role, int s9, int u) {
    int n = 0;
    for (int s = 0; s < s9; ++s) n += role_nt(role, s);
    return n + u;
}

// Compute from pre-loaded b registers (loaded at iteration top, before the
// x-prefetch, so vmcnt FIFO order is [b, x-next] and both overlap).
template<int ROLE, int R>
__device__ __forceinline__ void compute_role(const signed char* xsb,
                                             const int4v (&breg)[13],
                                             int16v (&acc)[R][2], const int (&p0)[R],
                                             int half) {
    #pragma unroll
    for (int s9 = 0; s9 < 9; ++s9) {
        if (role_nt(ROLE, s9) == 0) continue;
        const int dy = s9 / 3, dx = s9 % 3;
        int4v a[R];
        #pragma unroll
        for (int r = 0; r < R; ++r)
            a[r] = *(const int4v*)&xsb[(p0[r] + dy * 18 + dx) * 48 + half * 16];
        #pragma unroll
        for (int u = 0; u < 2; ++u) {
            if (u < role_nt(ROLE, s9)) {
                const int4v b = breg[role_bidx(ROLE, s9, u)];
                const int ai = role_acc(ROLE, s9, u);
                #pragma unroll
                for (int r = 0; r < R; ++r)
                    acc[r][ai] = __builtin_amdgcn_mfma_i32_32x32x32_i8(a[r], b, acc[r][ai], 0, 0, 0);
            }
        }
    }
}

// Layers 1-3: MW waves = MW/2 pairs x R subtiles -> (MW/2*R*2) quad-rows x
// 16 cols x 32 co. x-tile double-buffered in LDS (1 barrier/chunk);
// B prefetched to registers at iteration top. launch_bounds(256,2): breg
// adds ~52 VGPR; don't force spills (actual occupancy set by real usage).
template<int MW, int R>
__global__ __launch_bounds__(MW * 64, 2)
void deconv_v10(const signed char* __restrict__ xin, const signed char* __restrict__ wpk,
                const float* __restrict__ bias, const float* __restrict__ muls,
                const int* __restrict__ tsum,
                const float* __restrict__ relus, const int* __restrict__ dvds,
                const int* __restrict__ bitsp, const signed char* __restrict__ xpad,
                int layer, int Cin, int Cout, int NT, int Hq, int Wq,
                signed char* __restrict__ outp) {
    constexpr int PAIRS = MW / 2;
    constexpr int NROW = PAIRS * R * 2 + 2;
    constexpr int NPIX = NROW * 18;
    constexpr int THREADS = MW * 64;
    constexpr int XC = NPIX * 2;
    constexpr int XI = (XC + THREADS - 1) / THREADS;

    __shared__ __align__(16) signed char xs[2][NPIX * 48];

    const int tid  = threadIdx.x;
    const int lane = tid & 63;
    const int wid  = tid >> 6;
    const int pairId = wid >> 1;
    const int role   = wid & 1;
    const int qx0  = blockIdx.y * 16;
    const int qy0  = blockIdx.z * (PAIRS * R * 2);
    const int nb   = blockIdx.x;
    const int n0   = nb * 32;

    int16v acc[R][2];
    #pragma unroll
    for (int r = 0; r < R; ++r)
        #pragma unroll
        for (int p = 0; p < 2; ++p)
            #pragma unroll
            for (int e = 0; e < 16; ++e) acc[r][p][e] = 0;

    const int half   = lane >> 5;
    const int rowbit = (lane >> 4) & 1;
    const int col    = lane & 15;
    int p0[R];
    #pragma unroll
    for (int r = 0; r < R; ++r)
        p0[r] = ((pairId * R + r) * 2 + rowbit) * 18 + col;

    // hoisted staging addresses; OOB lanes redirected to the -128 pad region
    const signed char* xptr[XI];
    int  xsoff[XI];
    #pragma unroll
    for (int t = 0; t < XI; ++t) {
        int i = tid + t * THREADS;
        xsoff[t] = 0; xptr[t] = xpad;
        if (i < XC) {
            int pix = i >> 1, g = i & 1;
            int rr = pix / 18, cc = pix - rr * 18;
            int y = qy0 - 1 + rr, xx = qx0 - 1 + cc;
            xsoff[t] = pix * 48 + g * 16;
            bool ok = (unsigned)y < (unsigned)Hq && (unsigned)xx < (unsigned)Wq;
            xptr[t] = ok ? (xin + ((size_t)y * Wq + xx) * Cin + g * 16)
                         : (xpad + g * 16);
        }
    }

    int4v xreg[XI];
    int4v breg[13];

    auto load_x = [&](int ck) {
        #pragma unroll
        for (int t = 0; t < XI; ++t) {
            int i = tid + t * THREADS;
            if (i < XC) xreg[t] = *(const int4v*)(xptr[t] + ck);
        }
    };
    auto store_x = [&](int buf) {
        #pragma unroll
        for (int t = 0; t < XI; ++t) {
            int i = tid + t * THREADS;
            if (i < XC) *(int4v*)&xs[buf][xsoff[t]] = xreg[t];
        }
    };
    auto load_b = [&](const signed char* wslab) {
        if (role == 0) {
            #pragma unroll
            for (int s9 = 0; s9 < 9; ++s9)
                #pragma unroll
                for (int u = 0; u < 2; ++u)
                    if (u < role_nt(0, s9))
                        breg[role_bidx(0, s9, u)] =
                            *(const int4v*)&wslab[role_tap(0, s9, u) * 1024 + lane * 16];
        } else {
            #pragma unroll
            for (int s9 = 0; s9 < 9; ++s9)
                #pragma unroll
                for (int u = 0; u < 2; ++u)
                    if (u < role_nt(1, s9))
                        breg[role_bidx(1, s9, u)] =
                            *(const int4v*)&wslab[role_tap(1, s9, u) * 1024 + lane * 16];
        }
    };

    load_x(0);
    int buf = 0;
    for (int ck = 0; ck < Cin; ck += 32, buf ^= 1) {
        const signed char* wslab = wpk + (size_t)((ck >> 5) * NT + nb) * 25600;
        load_b(wslab);           // b global loads FIRST (vmcnt order: [b, x-next])
        store_x(buf);            // waits x(ck) via vmcnt(13); b stays in flight
        __syncthreads();
        if (ck + 32 < Cin) load_x(ck + 32);   // in flight through MFMA phase
        if (role == 0) compute_role<0, R>(xs[buf], breg, acc, p0, half);
        else           compute_role<1, R>(xs[buf], breg, acc, p0, half);
    }

    // ----- quant epilogue (exact fp32 op sequence; proven absmax 0.0) --------
    const int dv = dvds[layer];
    float add1 = ldexpf(1.0f, dv - 10);
    float inv1 = ldexpf(1.0f, -(dv - 9));
    const float relu = relus[layer];
    const int sk = (layer == 1) ? 4 : 3;
    const float bitsv = ldexpf(1.0f, bitsp[0]) - 1.0f;
    float clp, scl;
    {
        #pragma clang fp contract(off)
        clp = rintf(bitsv / relu * 33554432.0f);
        scl = floorf((relu + ldexpf(1.0f, sk - 1)) * ldexpf(1.0f, -sk));
    }
    float add2 = ldexpf(1.0f, 24 - sk);
    float inv2 = ldexpf(1.0f, -(25 - sk));

    const int co = n0 + (lane & 31);
    float bq = rintf(bias[co]);
    float mm = muls[co];
    // wave's two parities: role0 -> {EE=0, OO=3}; role1 -> {EO=1, OE=2}
    int pmap[2];
    pmap[0] = role == 0 ? 0 : 1;
    pmap[1] = role == 0 ? 3 : 2;
    int fullp[2];
    #pragma unroll
    for (int a = 0; a < 2; ++a) fullp[a] = tsum[pmap[a] * Cout + co];

    const int Wout = Wq * 2;

    #pragma unroll
    for (int r = 0; r < R; ++r) {
        #pragma unroll
        for (int a = 0; a < 2; ++a) {
            const int p = pmap[a];
            const int py = p >> 1, px = p & 1;
            #pragma unroll
            for (int reg = 0; reg < 16; ++reg) {
                const int mrow = (reg & 3) + 8 * (reg >> 2) + 4 * (lane >> 5);
                const int qy = qy0 + (pairId * R + r) * 2 + (mrow >> 4);
                const int qx = qx0 + (mrow & 15);
                float v = (float)(acc[r][a][reg] + 128 * fullp[a]);
                int iv;
                {
                    #pragma clang fp contract(off)
                    v = (v + bq) * mm;
                    v = floorf((v + add1) * inv1);
                    v = fminf(fmaxf(v, 0.0f), clp);
                    iv = (int)((v * scl + add2) * inv2);   // trunc == floor (v>=0)
                }
                const int oy = 2 * qy + py, ox = 2 * qx + px;
                outp[((size_t)oy * Wout + ox) * Cout + co] = (signed char)(iv - 128);
            }
        }
    }
}

// Final layer: N = (parity,co) columns, 1 MFMA per shift, R=2, MW=4,
// b prefetched to regs (same vmcnt-order fix), x-dbuf in LDS.
__global__ __launch_bounds__(256, 3)
void deconv_final_v10(const signed char* __restrict__ xin, const signed char* __restrict__ wpk,
                      const float* __restrict__ bias, const float* __restrict__ muls,
                      const int* __restrict__ tsum, const int* __restrict__ dvds,
                      const signed char* __restrict__ xpad,
                      int Cin, int Hq, int Wq, float* __restrict__ outp) {
    constexpr int R = 2, MW = 4;
    constexpr int NROW = MW * R * 2 + 2;   // 18
    constexpr int NPIX = NROW * 18;        // 324
    constexpr int THREADS = 256;
    constexpr int XC = NPIX * 2;           // 648
    constexpr int XI = (XC + THREADS - 1) / THREADS;   // 3

    __shared__ __align__(16) signed char xs[2][NPIX * 48];

    const int tid  = threadIdx.x;
    const int lane = tid & 63;
    const int wid  = tid >> 6;
    const int qx0  = blockIdx.y * 16;
    const int qy0  = blockIdx.z * (MW * R * 2);

    int16v acc[R];
    #pragma unroll
    for (int r = 0; r < R; ++r)
        #pragma unroll
        for (int e = 0; e < 16; ++e) acc[r][e] = 0;

    const int half   = lane >> 5;
    const int rowbit = (lane >> 4) & 1;
    const int col    = lane & 15;
    int p0[R];
    #pragma unroll
    for (int r = 0; r < R; ++r)
        p0[r] = ((wid * R + r) * 2 + rowbit) * 18 + col;

    const signed char* xptr[XI];
    int  xsoff[XI];
    #pragma unroll
    for (int t = 0; t < XI; ++t) {
        int i = tid + t * THREADS;
        xsoff[t] = 0; xptr[t] = xpad;
        if (i < XC) {
            int pix = i >> 1, g = i & 1;
            int rr = pix / 18, cc = pix - rr * 18;
            int y = qy0 - 1 + rr, xx = qx0 - 1 + cc;
            xsoff[t] = pix * 48 + g * 16;
            bool ok = (unsigned)y < (unsigned)Hq && (unsigned)xx < (unsigned)Wq;
            xptr[t] = ok ? (xin + ((size_t)y * Wq + xx) * Cin + g * 16)
                         : (xpad + g * 16);
        }
    }

    int4v xreg[XI];
    int4v breg[9];

    auto load_x = [&](int ck) {
        #pragma unroll
        for (int t = 0; t < XI; ++t) {
            int i = tid + t * THREADS;
            if (i < XC) xreg[t] = *(const int4v*)(xptr[t] + ck);
        }
    };
    auto store_x = [&](int buf) {
        #pragma unroll
        for (int t = 0; t < XI; ++t) {
            int i = tid + t * THREADS;
            if (i < XC) *(int4v*)&xs[buf][xsoff[t]] = xreg[t];
        }
    };
    auto load_b = [&](const signed char* wslab) {
        #pragma unroll
        for (int s9 = 0; s9 < 9; ++s9)
            breg[s9] = *(const int4v*)&wslab[s9 * 1024 + lane * 16];
    };

    load_x(0);
    int buf = 0;
    for (int ck = 0; ck < Cin; ck += 32, buf ^= 1) {
        const signed char* wslab = wpk + (size_t)(ck >> 5) * 9216;
        load_b(wslab);           // b first in vmcnt order
        store_x(buf);
        __syncthreads();
        if (ck + 32 < Cin) load_x(ck + 32);

        #pragma unroll
        for (int s9 = 0; s9 < 9; ++s9) {
            const int dy = s9 / 3, dx = s9 % 3;
            const int4v b = breg[s9];
            #pragma unroll
            for (int r = 0; r < R; ++r) {
                int4v a = *(const int4v*)&xs[buf][(p0[r] + dy * 18 + dx) * 48 + half * 16];
                acc[r] = __builtin_amdgcn_mfma_i32_32x32x32_i8(a, b, acc[r], 0, 0, 0);
            }
        }
    }

    const int dv = dvds[3];
    const float add1 = ldexpf(1.0f, dv - 9);
    const float inv1 = ldexpf(1.0f, -(dv - 8));

    const int coln = lane & 31;
    const int co = coln & 7;
    const int p  = coln >> 3;
    const int py = p >> 1, px = p & 1;
    const bool valid = (co < 3);
    float bq = 0.f, mm = 0.f;
    int fp = 0;
    if (valid) { bq = rintf(bias[co]); mm = muls[co]; fp = tsum[p * 3 + co]; }

    const int Wout = Wq * 2, Hout = Hq * 2;
    #pragma unroll
    for (int r = 0; r < R; ++r) {
        #pragma unroll
        for (int reg = 0; reg < 16; ++reg) {
            const int mrow = (reg & 3) + 8 * (reg >> 2) + 4 * (lane >> 5);
            const int qy = qy0 + (wid * R + r) * 2 + (mrow >> 4);
            const int qx = qx0 + (mrow & 15);
            float v = (float)(acc[r][reg] + 128 * fp);
            {
                #pragma clang fp contract(off)
                v = (v + bq) * mm;
                v = floorf((v + add1) * inv1);   // keep floorf: v may be negative
                v = v / 255.0f;
            }
            if (valid) {
                const int oy = 2 * qy + py, ox = 2 * qx + px;
                outp[((size_t)co * Hout + oy) * Wout + ox] = v;
            }
        }
    }
}

extern "C" void kernel_launch(void* const* d_in, const int* in_sizes, int n_in,
                              void* d_out, int out_size, void* d_ws, size_t ws_size,
                              hipStream_t stream) {
    const float* x  = (const float*)d_in[0];
    const float* w1 = (const float*)d_in[1];
    const float* b1 = (const float*)d_in[2];
    const float* w2 = (const float*)d_in[3];
    const float* b2 = (const float*)d_in[4];
    const float* w3 = (const float*)d_in[5];
    const float* b3 = (const float*)d_in[6];
    const float* w4 = (const float*)d_in[7];
    const float* b4 = (const float*)d_in[8];
    const float* m0 = (const float*)d_in[9];
    const float* m1 = (const float*)d_in[10];
    const float* m2 = (const float*)d_in[11];
    const float* m3 = (const float*)d_in[12];
    const float* relus = (const float*)d_in[13];
    const int* dvds = (const int*)d_in[14];
    const int* bitsp = (const int*)d_in[15];

    signed char* wsb = (signed char*)d_ws;
    size_t o = 0;
    signed char* wpk1 = wsb + o; o += (size_t)10 * 6 * 25600;   // 1,536,000
    signed char* wpk2 = wsb + o; o += (size_t)6 * 6 * 25600;    //   921,600
    signed char* wpk3 = wsb + o; o += (size_t)6 * 6 * 25600;
    signed char* wpk4 = wsb + o; o += (size_t)6 * 9216;         //    55,296
    int* ts1 = (int*)(wsb + o); o += 4 * 192 * 4;
    int* ts2 = (int*)(wsb + o); o += 4 * 192 * 4;
    int* ts3 = (int*)(wsb + o); o += 4 * 192 * 4;
    int* ts4 = (int*)(wsb + o); o += 4 * 4 * 4;
    o = (o + 15) & ~(size_t)15;
    signed char* xpad = wsb + o; o += 512;                      // -128 halo pad
    signed char* xh = wsb + o; o += (size_t)48 * 48 * 320;
    signed char* a1 = wsb + o; o += (size_t)96 * 96 * 192;
    signed char* a2 = wsb + o; o += (size_t)192 * 192 * 192;
    signed char* a3 = wsb + o; o += (size_t)384 * 384 * 192;

    const int ts_count = 4 * 192 * 3 + 4 * 4;   // ts1..ts4 contiguous ints

    convert_x_t<<<dim3(36, 5), 256, 0, stream>>>(x, xh, ts1, ts_count, 320, 48 * 48, xpad);
    packA<<<dim3(60, 3), 256, 0, stream>>>(w1, w2, w3, wpk1, wpk2, wpk3, ts1, ts2, ts3);
    pack_w4_i8<<<(6 * 9 * 1024 + 255) / 256, 256, 0, stream>>>(w4, wpk4);
    tap_w4<<<12, 64, 0, stream>>>(w4, ts4);

    // layer 1: 48x48x320 -> 96x96x192   (8-row tiles, 108 blocks, 256 thr)
    deconv_v10<4, 2><<<dim3(6, 3, 6), 256, 0, stream>>>(
        xh, wpk1, b1, m0, ts1, relus, dvds, bitsp, xpad, 0, 320, 192, 6, 48, 48, a1);
    // layer 2: 96x96x192 -> 192x192x192 (8-row tiles, 432 blocks, 256 thr)
    deconv_v10<4, 2><<<dim3(6, 6, 12), 256, 0, stream>>>(
        a1, wpk2, b2, m1, ts2, relus, dvds, bitsp, xpad, 1, 192, 192, 6, 96, 96, a2);
    // layer 3: 192x192x192 -> 384x384x192 (8-row tiles, 1728 blocks, 256 thr)
    deconv_v10<4, 2><<<dim3(6, 12, 24), 256, 0, stream>>>(
        a2, wpk3, b3, m2, ts3, relus, dvds, bitsp, xpad, 2, 192, 192, 6, 192, 192, a3);
    // layer 4: 384x384x192 -> 3x768x768 (final, f32 NCHW, /255; 576 blocks)
    deconv_final_v10<<<dim3(1, 24, 24), 256, 0, stream>>>(
        a3, wpk4, b4, m3, ts4, dvds, xpad, 192, 384, 384, (float*)d_out);
}

// Round 4
// 212.868 us; speedup vs baseline: 1.9109x; 1.9109x over previous
//
#include <hip/hip_runtime.h>
#include <cmath>

// ---------------------------------------------------------------------------
// g_s: 4x chained conv_transpose2d(k=5,s=2,p=2,op=1) + integer quant epilogue.
// Hermite: sum_j floor((round(w)+j)/split) == round(w) -> one conv per layer.
// Exact i8: weights round(w) in [-127,127]; activations (x-128) in i8; OOB
// halo = -128 so conv_i8 = conv_ref(x) - 128*tapsum[parity][co] (exact i32).
//
// v11 = v8 (known-good 213us) + two additive changes:
//  POST-MORTEMS: v9 (b from global) lost to vmcnt FIFO serialization of the
//  x-prefetch; v10 (b in regs, reordered) lost to scratch spill (breg[13]+
//  xreg spilled: WRITE_SIZE 27.6->474MB, VGPR_Count 76). Conclusion: the b
//  duplication fix must cost ZERO registers ->
//  (a) b staged via __builtin_amdgcn_global_load_lds DMA into bs[2] double
//      buffer: deletes 1600 global_load + 1600 ds_write per chunk-block, no
//      VGPR round-trip. DMA(next) issued after sync_B, lands during compute,
//      completion enforced by next __syncthreads()'s vmcnt(0) drain. Issue
//      order [load_x, dma_b] keeps DMA in flight across store_x's xreg wait.
//      LDS 66.7KB -> still 2 blocks/CU at MW=8.
//  (b) XCD-grouped remap for layer 3 (864 blocks = 144 tiles x 6 nb; hw
//      xcd=bid&7 -> give each XCD 18 contiguous tiles x all 6 nb; per-XCD
//      set 2.0MB < 4MB L2). L2-layer input fits one L2 -> no remap.
// ---------------------------------------------------------------------------

typedef int int4v  __attribute__((ext_vector_type(4)));
typedef int int16v __attribute__((ext_vector_type(16)));

#define GLOBAL_AS __attribute__((address_space(1)))
#define LDS_AS    __attribute__((address_space(3)))

// async global->LDS, 16B per lane; dest must be wave-uniform base + lane*16.
__device__ __forceinline__ void dma16(const signed char* g, signed char* l) {
    __builtin_amdgcn_global_load_lds((const GLOBAL_AS int*)g, (LDS_AS int*)l,
                                     16, 0, 0);
}

// tap id -> (ky,kx). Taps 0-8: EE; 9-14: EO; 15-20: OE; 21-24: OO.
__device__ __forceinline__ void tap_to_k(int t, int& ky, int& kx) {
    if (t < 9)       { int dy = t/3,  dx = t%3;                   ky = 4-2*dy; kx = 4-2*dx; }
    else if (t < 15) { int u = t-9;   int dy = u/2, dx = 1+(u&1);  ky = 4-2*dy; kx = 5-2*dx; }
    else if (t < 21) { int u = t-15;  int dy = 1+u/3, dx = u%3;    ky = 5-2*dy; kx = 4-2*dx; }
    else             { int u = t-21;  int dy = 1+u/2, dx = 1+(u&1); ky = 5-2*dy; kx = 5-2*dx; }
}

// f32 NCHW -> i8 (x-128) NHWC via LDS transpose; block(0,0) zeroes tapsums
__global__ __launch_bounds__(256)
void convert_x_t(const float* __restrict__ x, signed char* __restrict__ xh,
                 int* __restrict__ tsz, int ts_count, int C, int HW) {
    if (blockIdx.x == 0 && blockIdx.y == 0)
        for (int i = threadIdx.x; i < ts_count; i += 256) tsz[i] = 0;
    __shared__ float t[64][65];
    const int p0 = blockIdx.x * 64;
    const int c0 = blockIdx.y * 64;
    const int pL = threadIdx.x & 63;
    const int r0 = threadIdx.x >> 6;  // 0..3
    #pragma unroll
    for (int k = 0; k < 16; ++k) {
        int ciL = r0 * 16 + k;
        t[ciL][pL] = x[(size_t)(c0 + ciL) * HW + p0 + pL];
    }
    __syncthreads();
    #pragma unroll
    for (int k = 0; k < 16; ++k) {
        int pL2 = r0 * 16 + k;
        xh[(size_t)(p0 + pL2) * C + c0 + pL] = (signed char)((int)t[pL][pL2] - 128);
    }
}

// Fused pack+tapsum for layers 1-3. One block per 25600-B slab (qs,nb):
// stage the B-fragment slab in LDS (byte writes), copy out coalesced 16B;
// tapsum[p][co] reduced in LDS then one global atomicAdd per (p,co).
__global__ __launch_bounds__(256)
void packA(const float* __restrict__ w1, const float* __restrict__ w2,
           const float* __restrict__ w3,
           signed char* __restrict__ p1, signed char* __restrict__ p2,
           signed char* __restrict__ p3,
           int* __restrict__ t1, int* __restrict__ t2, int* __restrict__ t3) {
    const int layer = blockIdx.y;
    const float* w = (layer == 0) ? w1 : (layer == 1) ? w2 : w3;
    signed char* out = (layer == 0) ? p1 : (layer == 1) ? p2 : p3;
    int* ts = (layer == 0) ? t1 : (layer == 1) ? t2 : t3;
    const int Cout = 192;
    const int s = blockIdx.x;
    if (layer > 0 && s >= 36) return;
    const int qs = s / 6, nb = s % 6;

    __shared__ __align__(16) signed char ls[25600];
    __shared__ int lsum[4][32];
    if (threadIdx.x < 128) ((int*)lsum)[threadIdx.x] = 0;
    __syncthreads();

    #pragma unroll
    for (int k = 0; k < 4; ++k) {
        const int pidx = threadIdx.x + k * 256;   // 0..1023 = 32ci x 32co
        const int cil = pidx >> 5;
        const int col = pidx & 31;
        const int ci = qs * 32 + cil;
        const int co = nb * 32 + col;
        const float* wr = w + (size_t)(ci * Cout + co) * 25;
        const int half = cil >> 4, j = cil & 15;
        const int base = (half * 32 + col) * 16 + j;
        int psum[4] = {0, 0, 0, 0};
        #pragma unroll
        for (int t = 0; t < 25; ++t) {
            int ky, kx; tap_to_k(t, ky, kx);
            float v = rintf(wr[ky * 5 + kx]);
            v = fminf(fmaxf(v, -128.0f), 127.0f);
            int iv = (int)v;
            ls[t * 1024 + base] = (signed char)iv;
            psum[((ky & 1) << 1) | (kx & 1)] += iv;
        }
        #pragma unroll
        for (int p = 0; p < 4; ++p) atomicAdd(&lsum[p][col], psum[p]);
    }
    __syncthreads();

    signed char* dst = out + (size_t)s * 25600;
    for (int i = threadIdx.x; i < 1600; i += 256)
        *(int4v*)&dst[i * 16] = *(const int4v*)&ls[i * 16];
    if (threadIdx.x < 128) {
        const int p = threadIdx.x >> 5, col = threadIdx.x & 31;
        atomicAdd(&ts[p * Cout + nb * 32 + col], lsum[p][col]);
    }
}

// final-layer pack: N-dim = (parity,co): column c = p*8+co (co<3 live).
__global__ void pack_w4_i8(const float* __restrict__ w, signed char* __restrict__ wpk) {
    int idx = blockIdx.x * blockDim.x + threadIdx.x;
    if (idx >= 6 * 9 * 64 * 16) return;
    int j    = idx & 15;
    int lane = (idx >> 4) & 63;
    int rem  = idx >> 10;
    int s9   = rem % 9;
    int qs   = rem / 9;
    int col  = lane & 31;
    int co   = col & 7;
    int p    = col >> 3;
    int py = p >> 1, px = p & 1;
    int dy = s9 / 3, dx = s9 % 3;
    int ci = qs * 32 + ((lane >> 5) << 4) + j;
    bool part = (py == 0 || dy >= 1) && (px == 0 || dx >= 1);
    float v = 0.0f;
    if (co < 3 && part) {
        int ky = py ? 5 - 2 * dy : 4 - 2 * dy;
        int kx = px ? 5 - 2 * dx : 4 - 2 * dx;
        v = rintf(w[(size_t)(ci * 3 + co) * 25 + ky * 5 + kx]);
        v = fminf(fmaxf(v, -128.0f), 127.0f);
    }
    wpk[idx] = (signed char)(int)v;
}

// tapsum for w4 only: one 64-thread block per (p,co), 12 blocks.
__global__ __launch_bounds__(64)
void tap_w4(const float* __restrict__ w, int* __restrict__ ts) {
    const int Cin = 192, Cout = 3;
    const int i = blockIdx.x;            // p*3 + co
    const int co = i % Cout, p = i / Cout;
    const int py = p >> 1, px = p & 1;
    const int nky = (5 - py + 1) >> 1;
    const int nkx = (5 - px + 1) >> 1;
    const int ntap = nky * nkx;
    int s = 0;
    for (int idx = threadIdx.x; idx < Cin * ntap; idx += 64) {
        const int ci = idx / ntap;
        const int u  = idx - ci * ntap;
        const int ky = py + 2 * (u / nkx);
        const int kx = px + 2 * (u % nkx);
        float v = rintf(w[(size_t)(ci * Cout + co) * 25 + ky * 5 + kx]);
        v = fminf(fmaxf(v, -128.0f), 127.0f);
        s += (int)v;
    }
    #pragma unroll
    for (int off = 32; off > 0; off >>= 1)
        s += __shfl_down(s, off, 64);
    if (threadIdx.x == 0) ts[i] = s;
}

// Per-role tap tables for parity-split (role0: EE(acc0)+OO(acc1);
// role1: EO(acc0)+OE(acc1)). Verified against the full shift/tap/parity map.
__device__ __forceinline__ constexpr int role_nt(int role, int s9) {
    constexpr int NT0[9] = {1,1,1,1,2,2,1,2,2};
    constexpr int NT1[9] = {0,1,1,1,2,2,1,2,2};
    return role == 0 ? NT0[s9] : NT1[s9];
}
__device__ __forceinline__ constexpr int role_tap(int role, int s9, int u) {
    constexpr int T0[9][2] = {{0,0},{1,0},{2,0},{3,0},{4,21},{5,22},{6,0},{7,23},{8,24}};
    constexpr int T1[9][2] = {{0,0},{9,0},{10,0},{15,0},{11,16},{12,17},{18,0},{13,19},{14,20}};
    return role == 0 ? T0[s9][u] : T1[s9][u];
}
__device__ __forceinline__ constexpr int role_acc(int role, int s9, int u) {
    constexpr int A0[9][2] = {{0,0},{0,0},{0,0},{0,0},{0,1},{0,1},{0,0},{0,1},{0,1}};
    constexpr int A1[9][2] = {{0,0},{0,0},{0,0},{1,0},{0,1},{0,1},{1,0},{0,1},{0,1}};
    return role == 0 ? A0[s9][u] : A1[s9][u];
}

template<int ROLE, int R>
__device__ __forceinline__ void compute_role(const signed char* xsb, const signed char* bsb,
                                             int16v (&acc)[R][2], const int (&p0)[R],
                                             int half, int lane) {
    #pragma unroll
    for (int s9 = 0; s9 < 9; ++s9) {
        if (role_nt(ROLE, s9) == 0) continue;
        const int dy = s9 / 3, dx = s9 % 3;
        int4v a[R];
        #pragma unroll
        for (int r = 0; r < R; ++r)
            a[r] = *(const int4v*)&xsb[(p0[r] + dy * 18 + dx) * 48 + half * 16];
        #pragma unroll
        for (int u = 0; u < 2; ++u) {
            if (u < role_nt(ROLE, s9)) {
                int4v b = *(const int4v*)&bsb[role_tap(ROLE, s9, u) * 1024 + lane * 16];
                const int ai = role_acc(ROLE, s9, u);
                #pragma unroll
                for (int r = 0; r < R; ++r)
                    acc[r][ai] = __builtin_amdgcn_mfma_i32_32x32x32_i8(a[r], b, acc[r][ai], 0, 0, 0);
            }
        }
    }
}

// Layers 1-3: MW waves = MW/2 pairs x R=2 subtiles -> (MW*2) quad-rows x
// 16 cols x 32 co. x register-prefetch; b via DMA into bs[2] (zero VGPR).
// 1-D grid; T8>0 enables XCD-grouped decode (tiles-per-XCD).
template<int MW, int R>
__global__ __launch_bounds__(MW * 64, MW == 8 ? 4 : 3)
void deconv_v11(const signed char* __restrict__ xin, const signed char* __restrict__ wpk,
                const float* __restrict__ bias, const float* __restrict__ muls,
                const int* __restrict__ tsum,
                const float* __restrict__ relus, const int* __restrict__ dvds,
                const int* __restrict__ bitsp,
                int layer, int Cin, int Cout, int NT, int Hq, int Wq,
                int NB, int NQX, int T8,
                signed char* __restrict__ outp) {
    constexpr int PAIRS = MW / 2;
    constexpr int NROW = PAIRS * R * 2 + 2;
    constexpr int NPIX = NROW * 18;
    constexpr int THREADS = MW * 64;
    constexpr int XC = NPIX * 2;
    constexpr int XI = (XC + THREADS - 1) / THREADS;
    constexpr int BC = 1600;                       // 16B chunks per b slab
    constexpr int BTI = (BC + THREADS - 1) / THREADS;

    __shared__ __align__(16) signed char xs[NPIX * 48];
    __shared__ __align__(16) signed char bs[2][25600];

    const int tid  = threadIdx.x;
    const int lane = tid & 63;
    const int wid  = tid >> 6;
    const int pairId = wid >> 1;
    const int role   = wid & 1;

    // grid decode (1-D); T8>0: XCD-grouped (hw xcd = bid & 7)
    int nb, qx, qy;
    {
        const int bi = blockIdx.x;
        if (T8 > 0) {
            const int xcd = bi & 7, j = bi >> 3;
            const int tl = j / NB, n = j - tl * NB;
            const int tile = xcd * T8 + tl;
            nb = n; qx = tile % NQX; qy = tile / NQX;
        } else {
            nb = bi % NB;
            const int s = bi / NB;
            qx = s % NQX; qy = s / NQX;
        }
    }
    const int qx0 = qx * 16;
    const int qy0 = qy * (PAIRS * R * 2);
    const int n0  = nb * 32;

    int16v acc[R][2];
    #pragma unroll
    for (int r = 0; r < R; ++r)
        #pragma unroll
        for (int p = 0; p < 2; ++p)
            #pragma unroll
            for (int e = 0; e < 16; ++e) acc[r][p][e] = 0;

    const int half   = lane >> 5;
    const int rowbit = (lane >> 4) & 1;
    const int col    = lane & 15;
    int p0[R];
    #pragma unroll
    for (int r = 0; r < R; ++r)
        p0[r] = ((pairId * R + r) * 2 + rowbit) * 18 + col;

    int4v xreg[XI];
    auto load_x = [&](int ck) {
        #pragma unroll
        for (int t = 0; t < XI; ++t) {
            int i = tid + t * THREADS;
            if (i < XC) {
                int pix = i >> 1, g = i & 1;
                int rr = pix / 18, cc = pix - rr * 18;
                int y = qy0 - 1 + rr, xx = qx0 - 1 + cc;
                int4v v = {(int)0x80808080, (int)0x80808080,
                           (int)0x80808080, (int)0x80808080};
                if ((unsigned)y < (unsigned)Hq && (unsigned)xx < (unsigned)Wq)
                    v = *(const int4v*)&xin[((size_t)y * Wq + xx) * Cin + ck + g * 16];
                xreg[t] = v;
            }
        }
    };
    auto store_x = [&]() {
        #pragma unroll
        for (int t = 0; t < XI; ++t) {
            int i = tid + t * THREADS;
            if (i < XC) {
                int pix = i >> 1, g = i & 1;
                *(int4v*)&xs[pix * 48 + g * 16] = xreg[t];
            }
        }
    };
    auto dma_b = [&](const signed char* wslab, signed char* dst) {
        #pragma unroll
        for (int t = 0; t < BTI; ++t) {
            int i = tid + t * THREADS;
            if (i < BC)                       // BC multiple of 64: wave-uniform
                dma16(wslab + (size_t)i * 16, dst + (size_t)i * 16);
        }
    };

    load_x(0);
    dma_b(wpk + (size_t)nb * 25600, bs[0]);
    for (int ck = 0; ck < Cin; ck += 32) {
        const int cbuf = (ck >> 5) & 1;
        __syncthreads();          // sync_A: prev compute done reading xs/bs
        store_x();                // waits xreg only (DMA stays in flight)
        __syncthreads();          // sync_B: xs visible; vmcnt(0) -> DMA(cur) done
        if (ck + 32 < Cin) {
            load_x(ck + 32);      // x first, then DMA: store_x(next) won't drain DMA
            dma_b(wpk + (size_t)(((ck >> 5) + 1) * NT + nb) * 25600, bs[cbuf ^ 1]);
        }
        if (role == 0) compute_role<0, R>(xs, bs[cbuf], acc, p0, half, lane);
        else           compute_role<1, R>(xs, bs[cbuf], acc, p0, half, lane);
    }

    // ----- quant epilogue (exact fp32 op sequence; proven absmax 0.0) --------
    const int dv = dvds[layer];
    float add1 = ldexpf(1.0f, dv - 10);
    float inv1 = ldexpf(1.0f, -(dv - 9));
    const float relu = relus[layer];
    const int sk = (layer == 1) ? 4 : 3;
    const float bitsv = ldexpf(1.0f, bitsp[0]) - 1.0f;
    float clp, scl;
    {
        #pragma clang fp contract(off)
        clp = rintf(bitsv / relu * 33554432.0f);
        scl = floorf((relu + ldexpf(1.0f, sk - 1)) * ldexpf(1.0f, -sk));
    }
    float add2 = ldexpf(1.0f, 24 - sk);
    float inv2 = ldexpf(1.0f, -(25 - sk));

    const int co = n0 + (lane & 31);
    float bq = rintf(bias[co]);
    float mm = muls[co];
    // wave's two parities: role0 -> {EE=0, OO=3}; role1 -> {EO=1, OE=2}
    int pmap[2];
    pmap[0] = role == 0 ? 0 : 1;
    pmap[1] = role == 0 ? 3 : 2;
    int fullp[2];
    #pragma unroll
    for (int a = 0; a < 2; ++a) fullp[a] = tsum[pmap[a] * Cout + co];

    const int Wout = Wq * 2;

    #pragma unroll
    for (int r = 0; r < R; ++r) {
        #pragma unroll
        for (int a = 0; a < 2; ++a) {
            const int p = pmap[a];
            const int py = p >> 1, px = p & 1;
            #pragma unroll
            for (int reg = 0; reg < 16; ++reg) {
                const int mrow = (reg & 3) + 8 * (reg >> 2) + 4 * (lane >> 5);
                const int qy2 = qy0 + (pairId * R + r) * 2 + (mrow >> 4);
                const int qx2 = qx0 + (mrow & 15);
                float v = (float)(acc[r][a][reg] + 128 * fullp[a]);
                {
                    #pragma clang fp contract(off)
                    v = (v + bq) * mm;
                    v = floorf((v + add1) * inv1);
                    v = fminf(fmaxf(v, 0.0f), clp);
                    v = floorf((v * scl + add2) * inv2);
                }
                const int oy = 2 * qy2 + py, ox = 2 * qx2 + px;
                outp[((size_t)oy * Wout + ox) * Cout + co] = (signed char)((int)v - 128);
            }
        }
    }
}

// Final layer: N = (parity,co) columns, 1 MFMA per shift, R=2, MW=8,
// x register-prefetch; b via DMA into bs[2].
__global__ __launch_bounds__(512, 4)
void deconv_final_v11(const signed char* __restrict__ xin, const signed char* __restrict__ wpk,
                      const float* __restrict__ bias, const float* __restrict__ muls,
                      const int* __restrict__ tsum, const int* __restrict__ dvds,
                      int Cin, int Hq, int Wq, float* __restrict__ outp) {
    constexpr int R = 2, MW = 8;
    constexpr int NROW = MW * R * 2 + 2;   // 34
    constexpr int NPIX = NROW * 18;        // 612
    constexpr int THREADS = 512;
    constexpr int XC = NPIX * 2;           // 1224
    constexpr int XI = (XC + THREADS - 1) / THREADS;   // 3
    constexpr int BC = 576;                // 16B chunks per slab (multiple of 64)
    constexpr int BTI = (BC + THREADS - 1) / THREADS;  // 2

    __shared__ __align__(16) signed char xs[NPIX * 48];
    __shared__ __align__(16) signed char bs[2][9216];

    const int tid  = threadIdx.x;
    const int lane = tid & 63;
    const int wid  = tid >> 6;
    const int qx0  = blockIdx.y * 16;
    const int qy0  = blockIdx.z * (MW * R * 2);

    int16v acc[R];
    #pragma unroll
    for (int r = 0; r < R; ++r)
        #pragma unroll
        for (int e = 0; e < 16; ++e) acc[r][e] = 0;

    const int half   = lane >> 5;
    const int rowbit = (lane >> 4) & 1;
    const int col    = lane & 15;
    int p0[R];
    #pragma unroll
    for (int r = 0; r < R; ++r)
        p0[r] = ((wid * R + r) * 2 + rowbit) * 18 + col;

    int4v xreg[XI];
    auto load_x = [&](int ck) {
        #pragma unroll
        for (int t = 0; t < XI; ++t) {
            int i = tid + t * THREADS;
            if (i < XC) {
                int pix = i >> 1, g = i & 1;
                int rr = pix / 18, cc = pix - rr * 18;
                int y = qy0 - 1 + rr, xx = qx0 - 1 + cc;
                int4v v = {(int)0x80808080, (int)0x80808080,
                           (int)0x80808080, (int)0x80808080};
                if ((unsigned)y < (unsigned)Hq && (unsigned)xx < (unsigned)Wq)
                    v = *(const int4v*)&xin[((size_t)y * Wq + xx) * Cin + ck + g * 16];
                xreg[t] = v;
            }
        }
    };
    auto store_x = [&]() {
        #pragma unroll
        for (int t = 0; t < XI; ++t) {
            int i = tid + t * THREADS;
            if (i < XC) {
                int pix = i >> 1, g = i & 1;
                *(int4v*)&xs[pix * 48 + g * 16] = xreg[t];
            }
        }
    };
    auto dma_b = [&](const signed char* wslab, signed char* dst) {
        #pragma unroll
        for (int t = 0; t < BTI; ++t) {
            int i = tid + t * THREADS;
            if (i < BC)
                dma16(wslab + (size_t)i * 16, dst + (size_t)i * 16);
        }
    };

    load_x(0);
    dma_b(wpk, bs[0]);
    for (int ck = 0; ck < Cin; ck += 32) {
        const int cbuf = (ck >> 5) & 1;
        __syncthreads();
        store_x();
        __syncthreads();
        if (ck + 32 < Cin) {
            load_x(ck + 32);
            dma_b(wpk + (size_t)((ck >> 5) + 1) * 9216, bs[cbuf ^ 1]);
        }

        #pragma unroll
        for (int s9 = 0; s9 < 9; ++s9) {
            const int dy = s9 / 3, dx = s9 % 3;
            int4v b = *(const int4v*)&bs[cbuf][s9 * 1024 + lane * 16];
            #pragma unroll
            for (int r = 0; r < R; ++r) {
                int4v a = *(const int4v*)&xs[(p0[r] + dy * 18 + dx) * 48 + half * 16];
                acc[r] = __builtin_amdgcn_mfma_i32_32x32x32_i8(a, b, acc[r], 0, 0, 0);
            }
        }
    }

    const int dv = dvds[3];
    const float add1 = ldexpf(1.0f, dv - 9);
    const float inv1 = ldexpf(1.0f, -(dv - 8));

    const int coln = lane & 31;
    const int co = coln & 7;
    const int p  = coln >> 3;
    const int py = p >> 1, px = p & 1;
    const bool valid = (co < 3);
    float bq = 0.f, mm = 0.f;
    int fp = 0;
    if (valid) { bq = rintf(bias[co]); mm = muls[co]; fp = tsum[p * 3 + co]; }

    const int Wout = Wq * 2, Hout = Hq * 2;
    #pragma unroll
    for (int r = 0; r < R; ++r) {
        #pragma unroll
        for (int reg = 0; reg < 16; ++reg) {
            const int mrow = (reg & 3) + 8 * (reg >> 2) + 4 * (lane >> 5);
            const int qy = qy0 + (wid * R + r) * 2 + (mrow >> 4);
            const int qx = qx0 + (mrow & 15);
            float v = (float)(acc[r][reg] + 128 * fp);
            {
                #pragma clang fp contract(off)
                v = (v + bq) * mm;
                v = floorf((v + add1) * inv1);
                v = v / 255.0f;
            }
            if (valid) {
                const int oy = 2 * qy + py, ox = 2 * qx + px;
                outp[((size_t)co * Hout + oy) * Wout + ox] = v;
            }
        }
    }
}

extern "C" void kernel_launch(void* const* d_in, const int* in_sizes, int n_in,
                              void* d_out, int out_size, void* d_ws, size_t ws_size,
                              hipStream_t stream) {
    const float* x  = (const float*)d_in[0];
    const float* w1 = (const float*)d_in[1];
    const float* b1 = (const float*)d_in[2];
    const float* w2 = (const float*)d_in[3];
    const float* b2 = (const float*)d_in[4];
    const float* w3 = (const float*)d_in[5];
    const float* b3 = (const float*)d_in[6];
    const float* w4 = (const float*)d_in[7];
    const float* b4 = (const float*)d_in[8];
    const float* m0 = (const float*)d_in[9];
    const float* m1 = (const float*)d_in[10];
    const float* m2 = (const float*)d_in[11];
    const float* m3 = (const float*)d_in[12];
    const float* relus = (const float*)d_in[13];
    const int* dvds = (const int*)d_in[14];
    const int* bitsp = (const int*)d_in[15];

    signed char* wsb = (signed char*)d_ws;
    size_t o = 0;
    signed char* wpk1 = wsb + o; o += (size_t)10 * 6 * 25600;   // 1,536,000
    signed char* wpk2 = wsb + o; o += (size_t)6 * 6 * 25600;    //   921,600
    signed char* wpk3 = wsb + o; o += (size_t)6 * 6 * 25600;
    signed char* wpk4 = wsb + o; o += (size_t)6 * 9216;         //    55,296
    int* ts1 = (int*)(wsb + o); o += 4 * 192 * 4;
    int* ts2 = (int*)(wsb + o); o += 4 * 192 * 4;
    int* ts3 = (int*)(wsb + o); o += 4 * 192 * 4;
    int* ts4 = (int*)(wsb + o); o += 4 * 4 * 4;
    o = (o + 15) & ~(size_t)15;
    signed char* xh = wsb + o; o += (size_t)48 * 48 * 320;
    signed char* a1 = wsb + o; o += (size_t)96 * 96 * 192;
    signed char* a2 = wsb + o; o += (size_t)192 * 192 * 192;
    signed char* a3 = wsb + o; o += (size_t)384 * 384 * 192;

    const int ts_count = 4 * 192 * 3 + 4 * 4;   // ts1..ts4 contiguous ints

    convert_x_t<<<dim3(36, 5), 256, 0, stream>>>(x, xh, ts1, ts_count, 320, 48 * 48);
    packA<<<dim3(60, 3), 256, 0, stream>>>(w1, w2, w3, wpk1, wpk2, wpk3, ts1, ts2, ts3);
    pack_w4_i8<<<(6 * 9 * 1024 + 255) / 256, 256, 0, stream>>>(w4, wpk4);
    tap_w4<<<12, 64, 0, stream>>>(w4, ts4);

    // layer 1: 48x48x320 -> 96x96x192   (8-row tiles, 108 blocks, 256 thr)
    deconv_v11<4, 2><<<108, 256, 0, stream>>>(
        xh, wpk1, b1, m0, ts1, relus, dvds, bitsp, 0, 320, 192, 6, 48, 48,
        /*NB*/6, /*NQX*/3, /*T8*/0, a1);
    // layer 2: 96x96x192 -> 192x192x192 (16-row tiles, 216 blocks, 512 thr;
    // input+weights 2.7MB fit every XCD L2 -> no remap)
    deconv_v11<8, 2><<<216, 512, 0, stream>>>(
        a1, wpk2, b2, m1, ts2, relus, dvds, bitsp, 1, 192, 192, 6, 96, 96,
        6, 6, 0, a2);
    // layer 3: 192x192x192 -> 384x384x192 (16-row tiles, 864 blocks, 512 thr;
    // XCD-grouped: 144 tiles, 18 tiles/XCD x 6 nb -> 2.0MB/XCD L2-resident)
    deconv_v11<8, 2><<<864, 512, 0, stream>>>(
        a2, wpk3, b3, m2, ts3, relus, dvds, bitsp, 2, 192, 192, 6, 192, 192,
        6, 12, 18, a3);
    // layer 4: 384x384x192 -> 3x768x768 (final, f32 NCHW, /255; 288 blocks)
    deconv_final_v11<<<dim3(1, 24, 12), 512, 0, stream>>>(
        a3, wpk4, b4, m3, ts4, dvds, 192, 384, 384, (float*)d_out);
}

// Round 5
// 200.728 us; speedup vs baseline: 2.0265x; 1.0605x over previous
//
#include <hip/hip_runtime.h>
#include <cmath>

// ---------------------------------------------------------------------------
// g_s: 4x chained conv_transpose2d(k=5,s=2,p=2,op=1) + integer quant epilogue.
// Hermite: sum_j floor((round(w)+j)/split) == round(w) -> one conv per layer.
// Exact i8: weights round(w) in [-127,127]; activations (x-128) in i8; OOB
// halo = -128 so conv_i8 = conv_ref(x) - 128*tapsum[parity][co] (exact i32).
//
// v12 (from v11 @212.9us, L3 53.8): v11 post-mortem — FETCH 26->8MB worked but
// dur ~flat: never BW-bound; latency/pipe-mix bound + ~100us in small-grid
// layers/launches. Changes (additive):
//  (a) x staged via global_load_lds DMA too: xs stride 48->32 makes LDS dest
//      linear (i*16); src per-lane w/ OOB redirect to 512B 0x80 pad. Deletes
//      store_x + xreg; xs[2] dbuf -> ONE barrier per K-chunk (DMA issued
//      after barrier, lands during compute, drained by next barrier's
//      per-wave vmcnt(0)). Stride-32 a-reads: 8 accesses/bank = conflict-free.
//  (b) L2: 216x512thr -> 432x256 (MW=4); L4: 288x512 -> 576x256 -> ~2
//      resident blocks/CU so epilogue VALU overlaps other blocks' K-loops.
//  (c) packA+pack_w4+tap_w4 fused (8->6 launches). tapsum zeroing stays in
//      convert_x_t (kernel 1) -> no atomicAdd ordering race.
// ---------------------------------------------------------------------------

typedef int int4v  __attribute__((ext_vector_type(4)));
typedef int int16v __attribute__((ext_vector_type(16)));

#define GLOBAL_AS __attribute__((address_space(1)))
#define LDS_AS    __attribute__((address_space(3)))

// async global->LDS, 16B per lane; LDS dest linear in lane (base+lane*16).
__device__ __forceinline__ void dma16(const signed char* g, signed char* l) {
    __builtin_amdgcn_global_load_lds((const GLOBAL_AS int*)g, (LDS_AS int*)l,
                                     16, 0, 0);
}

// tap id -> (ky,kx). Taps 0-8: EE; 9-14: EO; 15-20: OE; 21-24: OO.
__device__ __forceinline__ void tap_to_k(int t, int& ky, int& kx) {
    if (t < 9)       { int dy = t/3,  dx = t%3;                   ky = 4-2*dy; kx = 4-2*dx; }
    else if (t < 15) { int u = t-9;   int dy = u/2, dx = 1+(u&1);  ky = 4-2*dy; kx = 5-2*dx; }
    else if (t < 21) { int u = t-15;  int dy = 1+u/3, dx = u%3;    ky = 5-2*dy; kx = 4-2*dx; }
    else             { int u = t-21;  int dy = 1+u/2, dx = 1+(u&1); ky = 5-2*dy; kx = 5-2*dx; }
}

// f32 NCHW -> i8 (x-128) NHWC via LDS transpose; block(0,0) zeroes tapsums
// and fills the 512B OOB pad with 0x80 (= -128). Must run before prep_pack.
__global__ __launch_bounds__(256)
void convert_x_t(const float* __restrict__ x, signed char* __restrict__ xh,
                 int* __restrict__ tsz, int ts_count, int C, int HW,
                 signed char* __restrict__ xpad) {
    if (blockIdx.x == 0 && blockIdx.y == 0) {
        for (int i = threadIdx.x; i < ts_count; i += 256) tsz[i] = 0;
        if (threadIdx.x < 128) ((int*)xpad)[threadIdx.x] = (int)0x80808080;
    }
    __shared__ float t[64][65];
    const int p0 = blockIdx.x * 64;
    const int c0 = blockIdx.y * 64;
    const int pL = threadIdx.x & 63;
    const int r0 = threadIdx.x >> 6;  // 0..3
    #pragma unroll
    for (int k = 0; k < 16; ++k) {
        int ciL = r0 * 16 + k;
        t[ciL][pL] = x[(size_t)(c0 + ciL) * HW + p0 + pL];
    }
    __syncthreads();
    #pragma unroll
    for (int k = 0; k < 16; ++k) {
        int pL2 = r0 * 16 + k;
        xh[(size_t)(p0 + pL2) * C + c0 + pL] = (signed char)((int)t[pL][pL2] - 128);
    }
}

// Fused prep: y<3 = packA(layer y); y==3: x<54 pack_w4 (4x256 elems each),
// x in [54,60): tap_w4 units (2 waves x 1 unit).
__global__ __launch_bounds__(256)
void prep_pack(const float* __restrict__ w1, const float* __restrict__ w2,
               const float* __restrict__ w3, const float* __restrict__ w4,
               signed char* __restrict__ p1, signed char* __restrict__ p2,
               signed char* __restrict__ p3, signed char* __restrict__ p4,
               int* __restrict__ t1, int* __restrict__ t2, int* __restrict__ t3,
               int* __restrict__ t4) {
    const int layer = blockIdx.y;
    if (layer == 3) {
        const int bx = blockIdx.x;
        if (bx < 54) {
            // pack_w4: N-dim = (parity,co): column c = p*8+co (co<3 live).
            #pragma unroll
            for (int k = 0; k < 4; ++k) {
                int idx = bx * 1024 + k * 256 + threadIdx.x;
                int j    = idx & 15;
                int lane = (idx >> 4) & 63;
                int rem  = idx >> 10;
                int s9   = rem % 9;
                int qs   = rem / 9;
                int col  = lane & 31;
                int co   = col & 7;
                int p    = col >> 3;
                int py = p >> 1, px = p & 1;
                int dy = s9 / 3, dx = s9 % 3;
                int ci = qs * 32 + ((lane >> 5) << 4) + j;
                bool part = (py == 0 || dy >= 1) && (px == 0 || dx >= 1);
                float v = 0.0f;
                if (co < 3 && part) {
                    int ky = py ? 5 - 2 * dy : 4 - 2 * dy;
                    int kx = px ? 5 - 2 * dx : 4 - 2 * dx;
                    v = rintf(w4[(size_t)(ci * 3 + co) * 25 + ky * 5 + kx]);
                    v = fminf(fmaxf(v, -128.0f), 127.0f);
                }
                p4[idx] = (signed char)(int)v;
            }
        } else if (threadIdx.x < 128) {
            // tap_w4: unit u = (bx-54)*2 + wave; 12 units of (p,co)
            const int Cin = 192, Cout = 3;
            const int u = (bx - 54) * 2 + (threadIdx.x >> 6);
            const int lane = threadIdx.x & 63;
            const int co = u % Cout, p = u / Cout;
            const int py = p >> 1, px = p & 1;
            const int nky = (5 - py + 1) >> 1;
            const int nkx = (5 - px + 1) >> 1;
            const int ntap = nky * nkx;
            int s = 0;
            for (int idx = lane; idx < Cin * ntap; idx += 64) {
                const int ci = idx / ntap;
                const int uu = idx - ci * ntap;
                const int ky = py + 2 * (uu / nkx);
                const int kx = px + 2 * (uu % nkx);
                float v = rintf(w4[(size_t)(ci * Cout + co) * 25 + ky * 5 + kx]);
                v = fminf(fmaxf(v, -128.0f), 127.0f);
                s += (int)v;
            }
            #pragma unroll
            for (int off = 32; off > 0; off >>= 1)
                s += __shfl_down(s, off, 64);
            if (lane == 0) t4[u] = s;
        }
        return;
    }
    // packA for layers 0-2
    const float* w = (layer == 0) ? w1 : (layer == 1) ? w2 : w3;
    signed char* out = (layer == 0) ? p1 : (layer == 1) ? p2 : p3;
    int* ts = (layer == 0) ? t1 : (layer == 1) ? t2 : t3;
    const int Cout = 192;
    const int s = blockIdx.x;
    if (layer > 0 && s >= 36) return;
    const int qs = s / 6, nb = s % 6;

    __shared__ __align__(16) signed char ls[25600];
    __shared__ int lsum[4][32];
    if (threadIdx.x < 128) ((int*)lsum)[threadIdx.x] = 0;
    __syncthreads();

    #pragma unroll
    for (int k = 0; k < 4; ++k) {
        const int pidx = threadIdx.x + k * 256;   // 0..1023 = 32ci x 32co
        const int cil = pidx >> 5;
        const int col = pidx & 31;
        const int ci = qs * 32 + cil;
        const int co = nb * 32 + col;
        const float* wr = w + (size_t)(ci * Cout + co) * 25;
        const int half = cil >> 4, j = cil & 15;
        const int base = (half * 32 + col) * 16 + j;
        int psum[4] = {0, 0, 0, 0};
        #pragma unroll
        for (int t = 0; t < 25; ++t) {
            int ky, kx; tap_to_k(t, ky, kx);
            float v = rintf(wr[ky * 5 + kx]);
            v = fminf(fmaxf(v, -128.0f), 127.0f);
            int iv = (int)v;
            ls[t * 1024 + base] = (signed char)iv;
            psum[((ky & 1) << 1) | (kx & 1)] += iv;
        }
        #pragma unroll
        for (int p = 0; p < 4; ++p) atomicAdd(&lsum[p][col], psum[p]);
    }
    __syncthreads();

    signed char* dst = out + (size_t)s * 25600;
    for (int i = threadIdx.x; i < 1600; i += 256)
        *(int4v*)&dst[i * 16] = *(const int4v*)&ls[i * 16];
    if (threadIdx.x < 128) {
        const int p = threadIdx.x >> 5, col = threadIdx.x & 31;
        atomicAdd(&ts[p * Cout + nb * 32 + col], lsum[p][col]);
    }
}

// Per-role tap tables for parity-split (role0: EE(acc0)+OO(acc1);
// role1: EO(acc0)+OE(acc1)). Verified against the full shift/tap/parity map.
__device__ __forceinline__ constexpr int role_nt(int role, int s9) {
    constexpr int NT0[9] = {1,1,1,1,2,2,1,2,2};
    constexpr int NT1[9] = {0,1,1,1,2,2,1,2,2};
    return role == 0 ? NT0[s9] : NT1[s9];
}
__device__ __forceinline__ constexpr int role_tap(int role, int s9, int u) {
    constexpr int T0[9][2] = {{0,0},{1,0},{2,0},{3,0},{4,21},{5,22},{6,0},{7,23},{8,24}};
    constexpr int T1[9][2] = {{0,0},{9,0},{10,0},{15,0},{11,16},{12,17},{18,0},{13,19},{14,20}};
    return role == 0 ? T0[s9][u] : T1[s9][u];
}
__device__ __forceinline__ constexpr int role_acc(int role, int s9, int u) {
    constexpr int A0[9][2] = {{0,0},{0,0},{0,0},{0,0},{0,1},{0,1},{0,0},{0,1},{0,1}};
    constexpr int A1[9][2] = {{0,0},{0,0},{0,0},{1,0},{0,1},{0,1},{1,0},{0,1},{0,1}};
    return role == 0 ? A0[s9][u] : A1[s9][u];
}

// xs layout: [pix][32B] (stride 32, linear for DMA); a-read at
// (p0+dy*18+dx)*32 + half*16 -> 8 accesses/bank across 64 lanes (no conflict)
template<int ROLE, int R>
__device__ __forceinline__ void compute_role(const signed char* xsb, const signed char* bsb,
                                             int16v (&acc)[R][2], const int (&p0)[R],
                                             int half, int lane) {
    #pragma unroll
    for (int s9 = 0; s9 < 9; ++s9) {
        if (role_nt(ROLE, s9) == 0) continue;
        const int dy = s9 / 3, dx = s9 % 3;
        int4v a[R];
        #pragma unroll
        for (int r = 0; r < R; ++r)
            a[r] = *(const int4v*)&xsb[(p0[r] + dy * 18 + dx) * 32 + half * 16];
        #pragma unroll
        for (int u = 0; u < 2; ++u) {
            if (u < role_nt(ROLE, s9)) {
                int4v b = *(const int4v*)&bsb[role_tap(ROLE, s9, u) * 1024 + lane * 16];
                const int ai = role_acc(ROLE, s9, u);
                #pragma unroll
                for (int r = 0; r < R; ++r)
                    acc[r][ai] = __builtin_amdgcn_mfma_i32_32x32x32_i8(a[r], b, acc[r][ai], 0, 0, 0);
            }
        }
    }
}

// Layers 1-3: MW waves = MW/2 pairs x R=2 subtiles. x AND b staged via DMA
// into double buffers; ONE barrier per K-chunk. OOB halo via xpad (+ck safe:
// pad is 512B of 0x80, ck+32 <= 320). T8>0: XCD-grouped block decode.
template<int MW, int R>
__global__ __launch_bounds__(MW * 64, 4)
void deconv_v12(const signed char* __restrict__ xin, const signed char* __restrict__ wpk,
                const float* __restrict__ bias, const float* __restrict__ muls,
                const int* __restrict__ tsum,
                const float* __restrict__ relus, const int* __restrict__ dvds,
                const int* __restrict__ bitsp, const signed char* __restrict__ xpad,
                int layer, int Cin, int Cout, int NT, int Hq, int Wq,
                int NB, int NQX, int T8,
                signed char* __restrict__ outp) {
    constexpr int PAIRS = MW / 2;
    constexpr int QROWS = PAIRS * R * 2;
    constexpr int NROW = QROWS + 2;
    constexpr int NPIX = NROW * 18;
    constexpr int THREADS = MW * 64;
    constexpr int XC = NPIX * 2;
    constexpr int XI = (XC + THREADS - 1) / THREADS;
    constexpr int BC = 1600;
    constexpr int BI = (BC + THREADS - 1) / THREADS;

    __shared__ __align__(16) signed char xs[2][NPIX * 32];
    __shared__ __align__(16) signed char bs[2][25600];

    const int tid  = threadIdx.x;
    const int lane = tid & 63;
    const int wid  = tid >> 6;
    const int pairId = wid >> 1;
    const int role   = wid & 1;

    int nb, qx, qy;
    {
        const int bi = blockIdx.x;
        if (T8 > 0) {
            const int xcd = bi & 7, j = bi >> 3;
            const int tl = j / NB, n = j - tl * NB;
            const int tile = xcd * T8 + tl;
            nb = n; qx = tile % NQX; qy = tile / NQX;
        } else {
            nb = bi % NB;
            const int s = bi / NB;
            qx = s % NQX; qy = s / NQX;
        }
    }
    const int qx0 = qx * 16;
    const int qy0 = qy * QROWS;
    const int n0  = nb * 32;

    int16v acc[R][2];
    #pragma unroll
    for (int r = 0; r < R; ++r)
        #pragma unroll
        for (int p = 0; p < 2; ++p)
            #pragma unroll
            for (int e = 0; e < 16; ++e) acc[r][p][e] = 0;

    const int half   = lane >> 5;
    const int rowbit = (lane >> 4) & 1;
    const int col    = lane & 15;
    int p0[R];
    #pragma unroll
    for (int r = 0; r < R; ++r)
        p0[r] = ((pairId * R + r) * 2 + rowbit) * 18 + col;

    // per-slot DMA source base (ck added later; OOB -> xpad, +ck stays in pad)
    const signed char* xsrc[XI];
    #pragma unroll
    for (int t = 0; t < XI; ++t) {
        int i = tid + t * THREADS;
        xsrc[t] = xpad;
        if (i < XC) {
            int pix = i >> 1, g = i & 1;
            int rr = pix / 18, cc = pix - rr * 18;
            int y = qy0 - 1 + rr, xx = qx0 - 1 + cc;
            bool ok = (unsigned)y < (unsigned)Hq && (unsigned)xx < (unsigned)Wq;
            xsrc[t] = ok ? (xin + ((size_t)y * Wq + xx) * Cin + g * 16)
                         : (xpad + g * 16);
        }
    }

    auto dma_x = [&](int ck, int b) {
        #pragma unroll
        for (int t = 0; t < XI; ++t) {
            int i = tid + t * THREADS;
            if (i < XC) dma16(xsrc[t] + ck, &xs[b][i * 16]);
        }
    };
    auto dma_b = [&](int cs, int b) {
        const signed char* ws = wpk + (size_t)(cs * NT + nb) * 25600;
        #pragma unroll
        for (int t = 0; t < BI; ++t) {
            int i = tid + t * THREADS;
            if (i < BC) dma16(ws + (size_t)i * 16, &bs[b][i * 16]);
        }
    };

    dma_x(0, 0);
    dma_b(0, 0);
    for (int ck = 0; ck < Cin; ck += 32) {
        const int cb = (ck >> 5) & 1;
        __syncthreads();   // per-wave vmcnt(0) drain -> DMA(cur) landed; and
                           // all waves done reading bufs before next overwrite
        if (ck + 32 < Cin) {
            dma_x(ck + 32, cb ^ 1);           // lands during compute
            dma_b((ck >> 5) + 1, cb ^ 1);
        }
        if (role == 0) compute_role<0, R>(xs[cb], bs[cb], acc, p0, half, lane);
        else           compute_role<1, R>(xs[cb], bs[cb], acc, p0, half, lane);
    }

    // ----- quant epilogue (exact fp32 op sequence; proven absmax 0.0) --------
    const int dv = dvds[layer];
    float add1 = ldexpf(1.0f, dv - 10);
    float inv1 = ldexpf(1.0f, -(dv - 9));
    const float relu = relus[layer];
    const int sk = (layer == 1) ? 4 : 3;
    const float bitsv = ldexpf(1.0f, bitsp[0]) - 1.0f;
    float clp, scl;
    {
        #pragma clang fp contract(off)
        clp = rintf(bitsv / relu * 33554432.0f);
        scl = floorf((relu + ldexpf(1.0f, sk - 1)) * ldexpf(1.0f, -sk));
    }
    float add2 = ldexpf(1.0f, 24 - sk);
    float inv2 = ldexpf(1.0f, -(25 - sk));

    const int co = n0 + (lane & 31);
    float bq = rintf(bias[co]);
    float mm = muls[co];
    // wave's two parities: role0 -> {EE=0, OO=3}; role1 -> {EO=1, OE=2}
    int pmap[2];
    pmap[0] = role == 0 ? 0 : 1;
    pmap[1] = role == 0 ? 3 : 2;
    int fullp[2];
    #pragma unroll
    for (int a = 0; a < 2; ++a) fullp[a] = tsum[pmap[a] * Cout + co];

    const int Wout = Wq * 2;

    #pragma unroll
    for (int r = 0; r < R; ++r) {
        #pragma unroll
        for (int a = 0; a < 2; ++a) {
            const int p = pmap[a];
            const int py = p >> 1, px = p & 1;
            #pragma unroll
            for (int reg = 0; reg < 16; ++reg) {
                const int mrow = (reg & 3) + 8 * (reg >> 2) + 4 * (lane >> 5);
                const int qy2 = qy0 + (pairId * R + r) * 2 + (mrow >> 4);
                const int qx2 = qx0 + (mrow & 15);
                float v = (float)(acc[r][a][reg] + 128 * fullp[a]);
                {
                    #pragma clang fp contract(off)
                    v = (v + bq) * mm;
                    v = floorf((v + add1) * inv1);
                    v = fminf(fmaxf(v, 0.0f), clp);
                    v = floorf((v * scl + add2) * inv2);
                }
                const int oy = 2 * qy2 + py, ox = 2 * qx2 + px;
                outp[((size_t)oy * Wout + ox) * Cout + co] = (signed char)((int)v - 128);
            }
        }
    }
}

// Final layer: N = (parity,co) columns, 1 MFMA per shift, R=2, MW=4 (576
// blocks -> ~2 resident/CU); x+b DMA double-buffered, one barrier per chunk.
__global__ __launch_bounds__(256, 4)
void deconv_final_v12(const signed char* __restrict__ xin, const signed char* __restrict__ wpk,
                      const float* __restrict__ bias, const float* __restrict__ muls,
                      const int* __restrict__ tsum, const int* __restrict__ dvds,
                      const signed char* __restrict__ xpad,
                      int Cin, int Hq, int Wq, float* __restrict__ outp) {
    constexpr int R = 2, MW = 4;
    constexpr int QROWS = MW * R * 2;      // 16
    constexpr int NROW = QROWS + 2;        // 18
    constexpr int NPIX = NROW * 18;        // 324
    constexpr int THREADS = 256;
    constexpr int XC = NPIX * 2;           // 648
    constexpr int XI = (XC + THREADS - 1) / THREADS;   // 3
    constexpr int BC = 576;
    constexpr int BI = (BC + THREADS - 1) / THREADS;   // 3

    __shared__ __align__(16) signed char xs[2][NPIX * 32];
    __shared__ __align__(16) signed char bs[2][9216];

    const int tid  = threadIdx.x;
    const int lane = tid & 63;
    const int wid  = tid >> 6;
    const int qx0  = blockIdx.y * 16;
    const int qy0  = blockIdx.z * QROWS;

    int16v acc[R];
    #pragma unroll
    for (int r = 0; r < R; ++r)
        #pragma unroll
        for (int e = 0; e < 16; ++e) acc[r][e] = 0;

    const int half   = lane >> 5;
    const int rowbit = (lane >> 4) & 1;
    const int col    = lane & 15;
    int p0[R];
    #pragma unroll
    for (int r = 0; r < R; ++r)
        p0[r] = ((wid * R + r) * 2 + rowbit) * 18 + col;

    const signed char* xsrc[XI];
    #pragma unroll
    for (int t = 0; t < XI; ++t) {
        int i = tid + t * THREADS;
        xsrc[t] = xpad;
        if (i < XC) {
            int pix = i >> 1, g = i & 1;
            int rr = pix / 18, cc = pix - rr * 18;
            int y = qy0 - 1 + rr, xx = qx0 - 1 + cc;
            bool ok = (unsigned)y < (unsigned)Hq && (unsigned)xx < (unsigned)Wq;
            xsrc[t] = ok ? (xin + ((size_t)y * Wq + xx) * Cin + g * 16)
                         : (xpad + g * 16);
        }
    }

    auto dma_x = [&](int ck, int b) {
        #pragma unroll
        for (int t = 0; t < XI; ++t) {
            int i = tid + t * THREADS;
            if (i < XC) dma16(xsrc[t] + ck, &xs[b][i * 16]);
        }
    };
    auto dma_b = [&](int cs, int b) {
        const signed char* ws = wpk + (size_t)cs * 9216;
        #pragma unroll
        for (int t = 0; t < BI; ++t) {
            int i = tid + t * THREADS;
            if (i < BC) dma16(ws + (size_t)i * 16, &bs[b][i * 16]);
        }
    };

    dma_x(0, 0);
    dma_b(0, 0);
    for (int ck = 0; ck < Cin; ck += 32) {
        const int cb = (ck >> 5) & 1;
        __syncthreads();
        if (ck + 32 < Cin) {
            dma_x(ck + 32, cb ^ 1);
            dma_b((ck >> 5) + 1, cb ^ 1);
        }
        #pragma unroll
        for (int s9 = 0; s9 < 9; ++s9) {
            const int dy = s9 / 3, dx = s9 % 3;
            int4v b = *(const int4v*)&bs[cb][s9 * 1024 + lane * 16];
            #pragma unroll
            for (int r = 0; r < R; ++r) {
                int4v a = *(const int4v*)&xs[cb][(p0[r] + dy * 18 + dx) * 32 + half * 16];
                acc[r] = __builtin_amdgcn_mfma_i32_32x32x32_i8(a, b, acc[r], 0, 0, 0);
            }
        }
    }

    const int dv = dvds[3];
    const float add1 = ldexpf(1.0f, dv - 9);
    const float inv1 = ldexpf(1.0f, -(dv - 8));

    const int coln = lane & 31;
    const int co = coln & 7;
    const int p  = coln >> 3;
    const int py = p >> 1, px = p & 1;
    const bool valid = (co < 3);
    float bq = 0.f, mm = 0.f;
    int fp = 0;
    if (valid) { bq = rintf(bias[co]); mm = muls[co]; fp = tsum[p * 3 + co]; }

    const int Wout = Wq * 2, Hout = Hq * 2;
    #pragma unroll
    for (int r = 0; r < R; ++r) {
        #pragma unroll
        for (int reg = 0; reg < 16; ++reg) {
            const int mrow = (reg & 3) + 8 * (reg >> 2) + 4 * (lane >> 5);
            const int qy = qy0 + (wid * R + r) * 2 + (mrow >> 4);
            const int qx = qx0 + (mrow & 15);
            float v = (float)(acc[r][reg] + 128 * fp);
            {
                #pragma clang fp contract(off)
                v = (v + bq) * mm;
                v = floorf((v + add1) * inv1);
                v = v / 255.0f;
            }
            if (valid) {
                const int oy = 2 * qy + py, ox = 2 * qx + px;
                outp[((size_t)co * Hout + oy) * Wout + ox] = v;
            }
        }
    }
}

extern "C" void kernel_launch(void* const* d_in, const int* in_sizes, int n_in,
                              void* d_out, int out_size, void* d_ws, size_t ws_size,
                              hipStream_t stream) {
    const float* x  = (const float*)d_in[0];
    const float* w1 = (const float*)d_in[1];
    const float* b1 = (const float*)d_in[2];
    const float* w2 = (const float*)d_in[3];
    const float* b2 = (const float*)d_in[4];
    const float* w3 = (const float*)d_in[5];
    const float* b3 = (const float*)d_in[6];
    const float* w4 = (const float*)d_in[7];
    const float* b4 = (const float*)d_in[8];
    const float* m0 = (const float*)d_in[9];
    const float* m1 = (const float*)d_in[10];
    const float* m2 = (const float*)d_in[11];
    const float* m3 = (const float*)d_in[12];
    const float* relus = (const float*)d_in[13];
    const int* dvds = (const int*)d_in[14];
    const int* bitsp = (const int*)d_in[15];

    signed char* wsb = (signed char*)d_ws;
    size_t o = 0;
    signed char* wpk1 = wsb + o; o += (size_t)10 * 6 * 25600;   // 1,536,000
    signed char* wpk2 = wsb + o; o += (size_t)6 * 6 * 25600;    //   921,600
    signed char* wpk3 = wsb + o; o += (size_t)6 * 6 * 25600;
    signed char* wpk4 = wsb + o; o += (size_t)6 * 9216;         //    55,296
    int* ts1 = (int*)(wsb + o); o += 4 * 192 * 4;
    int* ts2 = (int*)(wsb + o); o += 4 * 192 * 4;
    int* ts3 = (int*)(wsb + o); o += 4 * 192 * 4;
    int* ts4 = (int*)(wsb + o); o += 4 * 4 * 4;
    o = (o + 15) & ~(size_t)15;
    signed char* xpad = wsb + o; o += 512;                      // -128 halo pad
    signed char* xh = wsb + o; o += (size_t)48 * 48 * 320;
    signed char* a1 = wsb + o; o += (size_t)96 * 96 * 192;
    signed char* a2 = wsb + o; o += (size_t)192 * 192 * 192;
    signed char* a3 = wsb + o; o += (size_t)384 * 384 * 192;

    const int ts_count = 4 * 192 * 3 + 4 * 4;   // ts1..ts4 contiguous ints

    // kernel 1 (zeroes tapsums + fills xpad) must precede prep_pack's atomics
    convert_x_t<<<dim3(36, 5), 256, 0, stream>>>(x, xh, ts1, ts_count, 320, 48 * 48, xpad);
    // fused packA(3 layers) + pack_w4 + tap_w4
    prep_pack<<<dim3(60, 4), 256, 0, stream>>>(w1, w2, w3, w4,
                                               wpk1, wpk2, wpk3, wpk4,
                                               ts1, ts2, ts3, ts4);

    // layer 1: 48x48x320 -> 96x96x192   (8-row tiles, 108 blocks, 256 thr)
    deconv_v12<4, 2><<<108, 256, 0, stream>>>(
        xh, wpk1, b1, m0, ts1, relus, dvds, bitsp, xpad, 0, 320, 192, 6, 48, 48,
        /*NB*/6, /*NQX*/3, /*T8*/0, a1);
    // layer 2: 96x96x192 -> 192x192x192 (8-row tiles, 432 blocks, 256 thr)
    deconv_v12<4, 2><<<432, 256, 0, stream>>>(
        a1, wpk2, b2, m1, ts2, relus, dvds, bitsp, xpad, 1, 192, 192, 6, 96, 96,
        6, 6, 0, a2);
    // layer 3: 192x192x192 -> 384x384x192 (16-row tiles, 864 blocks, 512 thr;
    // XCD-grouped: 144 tiles, 18/XCD x 6 nb -> ~2MB/XCD L2-resident)
    deconv_v12<8, 2><<<864, 512, 0, stream>>>(
        a2, wpk3, b3, m2, ts3, relus, dvds, bitsp, xpad, 2, 192, 192, 6, 192, 192,
        6, 12, 18, a3);
    // layer 4: 384x384x192 -> 3x768x768 (final, f32 NCHW, /255; 576 blocks)
    deconv_final_v12<<<dim3(1, 24, 24), 256, 0, stream>>>(
        a3, wpk4, b4, m3, ts4, dvds, xpad, 192, 384, 384, (float*)d_out);
}